// Round 4
// baseline (124.567 us; speedup 1.0000x reference)
//
#include <hip/hip_runtime.h>
#include <hip/hip_bf16.h>

// DenseGridNet R4: two-pass.
//  Pass 1 gather_kernel: x + bilinear(emb fp32) -> packed bf16 in8 (d_ws), high
//    occupancy, 8 texel gathers in flight per thread-pair (latency-bound fix).
//  Pass 2 mlp_kernel: stream in8 -> MFMA 5->64->64->3 -> sigmoid -> out.
//  Fallback fused kernel if ws too small.

typedef __attribute__((ext_vector_type(8))) short bf16x8;
typedef __attribute__((ext_vector_type(4))) float f32x4;
typedef __attribute__((ext_vector_type(2))) unsigned int u32x2;
typedef __attribute__((ext_vector_type(4))) unsigned int u32x4;

#define HID 64

static __device__ __forceinline__ unsigned short f2bf(float f) {
    __hip_bfloat16 h = __float2bfloat16(f);
    return __builtin_bit_cast(unsigned short, h);
}
static __device__ __forceinline__ unsigned cvt_pk_bf16(float a, float b) {
    unsigned r;
    asm("v_cvt_pk_bf16_f32 %0, %1, %2" : "=v"(r) : "v"(a), "v"(b));
    return r;
}
static __device__ __forceinline__ void lds_fence() {
    asm volatile("s_waitcnt lgkmcnt(0)" ::: "memory");
}
#define MFMA16(a,b,c) __builtin_amdgcn_mfma_f32_16x16x32_bf16((a),(b),(c),0,0,0)

// byte offset into [64][64]-bf16 tile, XOR-swizzled (measured 0 conflicts)
static __device__ __forceinline__ int lswz(int row, int col_shorts) {
    return row * 128 + ((col_shorts * 2) ^ ((row & 7) << 4));
}

// ---------------- pass 1: bilinear gather -> packed bf16 in8 ----------------
__global__ __launch_bounds__(256, 4)
void gather_kernel(const float* __restrict__ x, const float* __restrict__ emb,
                   u32x4* __restrict__ in8, int n)
{
    const f32x4* __restrict__ emb4 = (const f32x4*)emb;
    const int stride = gridDim.x * 256;
    for (int p0 = blockIdx.x * 256 + threadIdx.x; p0 < n; p0 += 2 * stride) {
        const int p1  = p0 + stride;
        const bool h1 = p1 < n;
        const int p1c = h1 ? p1 : p0;
        const float* xp0 = x + 3 * p0;
        const float* xp1 = x + 3 * p1c;
        float i0 = xp0[0], u0 = xp0[1], v0 = xp0[2];
        float i1 = xp1[0], u1 = xp1[1], v1 = xp1[2];

        float uf0 = u0 * 1024.f, vf0 = v0 * 1024.f;
        float uf1 = u1 * 1024.f, vf1 = v1 * 1024.f;
        int xa0 = (int)uf0; if (xa0 == 1024) xa0 = 0;
        int xb0 = (xa0 + 1 == 1024) ? 1023 : xa0 + 1;
        int ya0 = (int)vf0;
        float wx0 = uf0 - (float)xa0, wy0 = vf0 - (float)ya0;
        if (ya0 > 1023) ya0 = 1023;
        int yb0 = (ya0 + 1 > 1023) ? 1023 : ya0 + 1;
        int xa1 = (int)uf1; if (xa1 == 1024) xa1 = 0;
        int xb1 = (xa1 + 1 == 1024) ? 1023 : xa1 + 1;
        int ya1 = (int)vf1;
        float wx1 = uf1 - (float)xa1, wy1 = vf1 - (float)ya1;
        if (ya1 > 1023) ya1 = 1023;
        int yb1 = (ya1 + 1 > 1023) ? 1023 : ya1 + 1;

        // issue all 8 texel loads, then lerp
        f32x4 A0 = emb4[(ya0 << 10) + xa0];
        f32x4 B0 = emb4[(ya0 << 10) + xb0];
        f32x4 C0 = emb4[(yb0 << 10) + xa0];
        f32x4 D0 = emb4[(yb0 << 10) + xb0];
        f32x4 A1 = emb4[(ya1 << 10) + xa1];
        f32x4 B1 = emb4[(ya1 << 10) + xb1];
        f32x4 C1 = emb4[(yb1 << 10) + xa1];
        f32x4 D1 = emb4[(yb1 << 10) + xb1];

        f32x4 up0 = A0 + (B0 - A0) * wx0;
        f32x4 dn0 = C0 + (D0 - C0) * wx0;
        f32x4 g0  = up0 + (dn0 - up0) * wy0;
        u32x4 o0 = {cvt_pk_bf16(i0, g0[0]), cvt_pk_bf16(g0[1], g0[2]),
                    cvt_pk_bf16(g0[3], 0.f), 0u};
        in8[p0] = o0;

        f32x4 up1 = A1 + (B1 - A1) * wx1;
        f32x4 dn1 = C1 + (D1 - C1) * wx1;
        f32x4 g1  = up1 + (dn1 - up1) * wy1;
        if (h1) {
            u32x4 o1 = {cvt_pk_bf16(i1, g1[0]), cvt_pk_bf16(g1[1], g1[2]),
                        cvt_pk_bf16(g1[3], 0.f), 0u};
            in8[p1] = o1;
        }
    }
}

// ---------------- shared: weight fragment setup via LDS staging ----------------
// Wst layout (floats): [0..4095]=w2, [4096..4415]=w1, [4416..4479]=b1,
//                      [4480..4671]=w3, [4672..4735]=b2, [4736..4738]=b3
#define STAGE_WEIGHTS(Wst, tid)                                                  \
    {                                                                            \
        const f32x4* w2v = (const f32x4*)w2;                                     \
        f32x4* Wv = (f32x4*)(Wst);                                               \
        _Pragma("unroll")                                                        \
        for (int i_ = 0; i_ < 4; ++i_) Wv[tid + 256 * i_] = w2v[tid + 256 * i_]; \
        for (int idx_ = tid; idx_ < 320; idx_ += 256) (Wst)[4096 + idx_] = w1[idx_]; \
        if (tid < 64)  (Wst)[4416 + tid] = b1[tid];                              \
        if (tid < 192) (Wst)[4480 + tid] = w3[tid];                              \
        if (tid < 64)  (Wst)[4672 + tid] = b2[tid];                              \
        if (tid < 3)   (Wst)[4736 + tid] = b3[tid];                              \
    }                                                                            \
    __syncthreads();

#define BUILD_FRAGS(Wst)                                                         \
    bf16x8 w1f[4];                                                               \
    _Pragma("unroll")                                                            \
    for (int nt = 0; nt < 4; ++nt) {                                             \
        bf16x8 f = {};                                                           \
        if (kg == 0) {                                                           \
            _Pragma("unroll")                                                    \
            for (int j = 0; j < 5; ++j)                                          \
                f[j] = (short)f2bf((Wst)[4096 + j * 64 + hb + nt]);              \
        }                                                                        \
        w1f[nt] = f;                                                             \
    }                                                                            \
    bf16x8 w2f[2][4];                                                            \
    _Pragma("unroll")                                                            \
    for (int ks = 0; ks < 2; ++ks) {                                             \
        f32x4 r[8];                                                              \
        _Pragma("unroll")                                                        \
        for (int j = 0; j < 8; ++j)                                              \
            r[j] = *(const f32x4*)&(Wst)[(ks * 32 + kg * 8 + j) * 64 + hb];      \
        _Pragma("unroll")                                                        \
        for (int nt = 0; nt < 4; ++nt) {                                         \
            u32x4 w;                                                             \
            _Pragma("unroll")                                                    \
            for (int jw = 0; jw < 4; ++jw)                                       \
                w[jw] = cvt_pk_bf16(r[2 * jw][nt], r[2 * jw + 1][nt]);           \
            w2f[ks][nt] = __builtin_bit_cast(bf16x8, w);                         \
        }                                                                        \
    }                                                                            \
    bf16x8 w3f[2];                                                               \
    _Pragma("unroll")                                                            \
    for (int ks = 0; ks < 2; ++ks) {                                             \
        bf16x8 f = {};                                                           \
        if (cl < 3) {                                                            \
            _Pragma("unroll")                                                    \
            for (int j = 0; j < 8; ++j)                                          \
                f[j] = (short)f2bf((Wst)[4480 + (ks * 32 + kg * 8 + j) * 3 + cl]); \
        }                                                                        \
        w3f[ks] = f;                                                             \
    }                                                                            \
    float b1v[4], b2v[4];                                                        \
    _Pragma("unroll")                                                            \
    for (int nt = 0; nt < 4; ++nt) {                                             \
        b1v[nt] = (Wst)[4416 + hb + nt];                                         \
        b2v[nt] = (Wst)[4672 + hb + nt];                                         \
    }                                                                            \
    const float b3v = (cl < 3) ? (Wst)[4736 + cl] : 0.f;                         \
    __syncthreads();

// the 3 MFMA layers + sigmoid + LDS out-staging for one 64-pt wave tile.
// expects: in8 tile already in Lin; leaves sigmoid outputs in Lo (192 floats).
#define MLP_BODY()                                                               \
    _Pragma("unroll")                                                            \
    for (int mt = 0; mt < 4; ++mt) {                                             \
        bf16x8 af = {};                                                          \
        if (kg == 0) af = *(const bf16x8*)(Lin + (mt * 16 + cl) * 8);            \
        f32x4 acc[4];                                                            \
        _Pragma("unroll")                                                        \
        for (int nt = 0; nt < 4; ++nt) {                                         \
            acc[nt] = (f32x4){b1v[nt], b1v[nt], b1v[nt], b1v[nt]};               \
            acc[nt] = MFMA16(af, w1f[nt], acc[nt]);                              \
        }                                                                        \
        _Pragma("unroll")                                                        \
        for (int r = 0; r < 4; ++r) {                                            \
            int row = mt * 16 + kg * 4 + r;                                      \
            u32x2 p = {cvt_pk_bf16(fmaxf(acc[0][r], 0.f), fmaxf(acc[1][r], 0.f)),\
                       cvt_pk_bf16(fmaxf(acc[2][r], 0.f), fmaxf(acc[3][r], 0.f))};\
            *(u32x2*)(LhB + lswz(row, hb)) = p;                                  \
        }                                                                        \
    }                                                                            \
    lds_fence();                                                                 \
    _Pragma("unroll")                                                            \
    for (int mt = 0; mt < 4; ++mt) {                                             \
        int arow = mt * 16 + cl;                                                 \
        bf16x8 a0 = *(const bf16x8*)(LhB + lswz(arow, kg * 8));                  \
        bf16x8 a1 = *(const bf16x8*)(LhB + lswz(arow, 32 + kg * 8));             \
        f32x4 acc[4];                                                            \
        _Pragma("unroll")                                                        \
        for (int nt = 0; nt < 4; ++nt) {                                         \
            acc[nt] = (f32x4){b2v[nt], b2v[nt], b2v[nt], b2v[nt]};               \
            acc[nt] = MFMA16(a0, w2f[0][nt], acc[nt]);                           \
            acc[nt] = MFMA16(a1, w2f[1][nt], acc[nt]);                           \
        }                                                                        \
        _Pragma("unroll")                                                        \
        for (int r = 0; r < 4; ++r) {                                            \
            int row = mt * 16 + kg * 4 + r;                                      \
            u32x2 p = {cvt_pk_bf16(fmaxf(acc[0][r], 0.f), fmaxf(acc[1][r], 0.f)),\
                       cvt_pk_bf16(fmaxf(acc[2][r], 0.f), fmaxf(acc[3][r], 0.f))};\
            *(u32x2*)(LhB + lswz(row, hb)) = p;                                  \
        }                                                                        \
    }                                                                            \
    lds_fence();                                                                 \
    _Pragma("unroll")                                                            \
    for (int mt = 0; mt < 4; ++mt) {                                             \
        int arow = mt * 16 + cl;                                                 \
        bf16x8 a0 = *(const bf16x8*)(LhB + lswz(arow, kg * 8));                  \
        bf16x8 a1 = *(const bf16x8*)(LhB + lswz(arow, 32 + kg * 8));             \
        f32x4 acc = (f32x4){b3v, b3v, b3v, b3v};                                 \
        acc = MFMA16(a0, w3f[0], acc);                                           \
        acc = MFMA16(a1, w3f[1], acc);                                           \
        if (cl < 3) {                                                            \
            _Pragma("unroll")                                                    \
            for (int r = 0; r < 4; ++r) {                                        \
                float t = acc[r];                                                \
                float s = __builtin_amdgcn_rcpf(1.0f + __expf(-t));              \
                Lo[(mt * 16 + kg * 4 + r) * 3 + cl] = s;                         \
            }                                                                    \
        }                                                                        \
    }                                                                            \
    lds_fence();

#define STORE_OUT(wbase)                                                         \
    if ((wbase) + 64 <= n) {                                                     \
        if (lane < 48)                                                           \
            *(f32x4*)(out + (wbase) * 3 + lane * 4) = *(const f32x4*)(Lo + lane * 4); \
    } else {                                                                     \
        int pt_ = (wbase) + lane;                                                \
        if (pt_ < n) {                                                           \
            out[pt_ * 3 + 0] = Lo[lane * 3 + 0];                                 \
            out[pt_ * 3 + 1] = Lo[lane * 3 + 1];                                 \
            out[pt_ * 3 + 2] = Lo[lane * 3 + 2];                                 \
        }                                                                        \
    }

// ---------------- pass 2: streaming MLP ----------------
__global__ __launch_bounds__(256, 3)
void mlp_kernel(const u32x4* __restrict__ in8,
                const float* __restrict__ w1, const float* __restrict__ b1,
                const float* __restrict__ w2, const float* __restrict__ b2,
                const float* __restrict__ w3, const float* __restrict__ b3,
                float* __restrict__ out, int n)
{
    __shared__ __align__(16) short lds_h[4][64][64];   // 32KB (also weight staging)
    __shared__ __align__(16) short lds_in[4][64][8];   //  4KB in8 / out staging

    const int tid = threadIdx.x, wid = tid >> 6, lane = tid & 63;
    const int cl = lane & 15, kg = lane >> 4, hb = cl * 4;
    char  *LhB = (char*)&lds_h[wid][0][0];
    short *Lin = &lds_in[wid][0][0];
    float *Lo  = (float*)Lin;

    float* Wst = (float*)&lds_h[0][0][0];
    STAGE_WEIGHTS(Wst, tid)
    BUILD_FRAGS(Wst)

    const int step = gridDim.x * 256;
    const int blk0 = blockIdx.x * 256;
    if (blk0 >= n) return;
    const int iters = (n - blk0 + step - 1) / step;
    const int wb0   = blk0 + wid * 64;

    u32x4 q;
    { int pt = wb0 + lane; int pc = pt < n ? pt : 0; q = in8[pc]; }

    for (int i = 0; i < iters; ++i) {
        const int wbase = wb0 + i * step;
        // prefetch next tile (issued before this tile's MFMA work)
        u32x4 qn;
        { int pt = wbase + step + lane; int pc = pt < n ? pt : 0; qn = in8[pc]; }

        *(u32x4*)(Lin + lane * 8) = q;
        lds_fence();
        MLP_BODY()
        STORE_OUT(wbase)
        q = qn;
    }
}

// ---------------- fallback: fused (ws too small) ----------------
__global__ __launch_bounds__(256, 3)
void dgn_fused(const float* __restrict__ x, const float* __restrict__ emb,
               const float* __restrict__ w1, const float* __restrict__ b1,
               const float* __restrict__ w2, const float* __restrict__ b2,
               const float* __restrict__ w3, const float* __restrict__ b3,
               float* __restrict__ out, int n)
{
    __shared__ __align__(16) short lds_h[4][64][64];
    __shared__ __align__(16) short lds_in[4][64][8];

    const int tid = threadIdx.x, wid = tid >> 6, lane = tid & 63;
    const int cl = lane & 15, kg = lane >> 4, hb = cl * 4;
    char  *LhB = (char*)&lds_h[wid][0][0];
    short *Lin = &lds_in[wid][0][0];
    float *Lo  = (float*)Lin;

    float* Wst = (float*)&lds_h[0][0][0];
    STAGE_WEIGHTS(Wst, tid)
    BUILD_FRAGS(Wst)

    const f32x4* __restrict__ emb4 = (const f32x4*)emb;

    for (int base = blockIdx.x * 256; base < n; base += gridDim.x * 256) {
        const int wbase = base + wid * 64;
        const int pt    = wbase + lane;
        float idf = 0.f, u = 0.f, vv = 0.f;
        if (pt < n) {
            const float* xp = x + 3 * pt;
            idf = xp[0]; u = xp[1]; vv = xp[2];
        }
        float uf = u * 1024.f, vf = vv * 1024.f;
        int x0 = (int)uf; if (x0 == 1024) x0 = 0;
        int x1i = (x0 + 1 == 1024) ? 1023 : x0 + 1;
        int y0 = (int)vf;
        float wx = uf - (float)x0, wy = vf - (float)y0;
        if (y0 > 1023) y0 = 1023;
        int y1 = (y0 + 1 > 1023) ? 1023 : y0 + 1;

        f32x4 v00 = emb4[(y0 << 10) + x0];
        f32x4 v10 = emb4[(y0 << 10) + x1i];
        f32x4 v01 = emb4[(y1 << 10) + x0];
        f32x4 v11 = emb4[(y1 << 10) + x1i];
        f32x4 vup = v00 + (v10 - v00) * wx;
        f32x4 vdn = v01 + (v11 - v01) * wx;
        f32x4 g   = vup + (vdn - vup) * wy;

        u32x4 inq = {cvt_pk_bf16(idf, g[0]), cvt_pk_bf16(g[1], g[2]),
                     cvt_pk_bf16(g[3], 0.f), 0u};
        *(u32x4*)(Lin + lane * 8) = inq;
        lds_fence();
        MLP_BODY()
        STORE_OUT(wbase)
    }
}

extern "C" void kernel_launch(void* const* d_in, const int* in_sizes, int n_in,
                              void* d_out, int out_size, void* d_ws, size_t ws_size,
                              hipStream_t stream) {
    const float* x   = (const float*)d_in[0];
    const float* emb = (const float*)d_in[1];
    const float* w1  = (const float*)d_in[2];
    const float* b1  = (const float*)d_in[3];
    const float* w2  = (const float*)d_in[4];
    const float* b2  = (const float*)d_in[5];
    const float* w3  = (const float*)d_in[6];
    const float* b3  = (const float*)d_in[7];
    float* out = (float*)d_out;

    int n = in_sizes[0] / 3;
    size_t need = (size_t)n * sizeof(u32x4);
    if (ws_size >= need) {
        int nthr  = (n + 1) / 2;
        int nblkA = (nthr + 255) / 256; if (nblkA > 8192) nblkA = 8192;
        gather_kernel<<<dim3(nblkA), dim3(256), 0, stream>>>(x, emb, (u32x4*)d_ws, n);
        int nblkB = (n + 255) / 256; if (nblkB > 2048) nblkB = 2048;
        mlp_kernel<<<dim3(nblkB), dim3(256), 0, stream>>>(
            (const u32x4*)d_ws, w1, b1, w2, b2, w3, b3, out, n);
    } else {
        int nblk = (n + 255) / 256; if (nblk > 2048) nblk = 2048;
        dgn_fused<<<dim3(nblk), dim3(256), 0, stream>>>(
            x, emb, w1, b1, w2, b2, w3, b3, out, n);
    }
}